// Round 1
// baseline (136375.781 us; speedup 1.0000x reference)
//
#include <hip/hip_runtime.h>
#include <math.h>

#define NBLK 128
#define NTHR 256
#define NPOS 3168     // 99 steps * 32 batch
#define NSTAGES 3174  // last proj-phase2 at s = 3167 + 6
#define HIDN 512
#define TT 2048
#define EE 64
#define VV 64
#define LL 100

__device__ __forceinline__ float aload(const float* p) {
  return __hip_atomic_load((float*)p, __ATOMIC_RELAXED, __HIP_MEMORY_SCOPE_AGENT);
}
__device__ __forceinline__ void astore(float* p, float v) {
  __hip_atomic_store(p, v, __ATOMIC_RELAXED, __HIP_MEMORY_SCOPE_AGENT);
}
__device__ __forceinline__ float wsum(float v) {
#pragma unroll
  for (int o = 32; o; o >>= 1) v += __shfl_xor(v, o);
  return v;
}
__device__ __forceinline__ float wmax(float v) {
#pragma unroll
  for (int o = 32; o; o >>= 1) v = fmaxf(v, __shfl_xor(v, o));
  return v;
}
__device__ __forceinline__ float sigm(float x) { return 1.f / (1.f + expf(-x)); }

extern "C" __global__ void speller_init(float* ws) {
  const int i = blockIdx.x * blockDim.x + threadIdx.x;
  if (i < 3200) ws[i] = 0.f;  // barrier cnt/gen + h double buffers
}

extern "C" __global__ __launch_bounds__(NTHR)
void speller_main(const float* __restrict__ ctx_t, const int* __restrict__ gt,
                  const float* __restrict__ emb, const float* __restrict__ w_out,
                  const float* __restrict__ b_out,
                  const float* __restrict__ wi0, const float* __restrict__ wh0,
                  const float* __restrict__ bi0, const float* __restrict__ bh0,
                  const float* __restrict__ wi1, const float* __restrict__ wh1,
                  const float* __restrict__ bi1, const float* __restrict__ bh1,
                  const float* __restrict__ wi2, const float* __restrict__ wh2,
                  const float* __restrict__ bi2, const float* __restrict__ bh2,
                  float* __restrict__ out, float* __restrict__ ws)
{
  const int bid = blockIdx.x, tid = threadIdx.x;
  const int lane = tid & 63, wv = tid >> 6;

  int* cnt = (int*)ws;
  int* gen = (int*)ws + 32;                 // separate cacheline from cnt
  float* h_buf   = ws + 64;                 // [2][3][512]
  float* ctx_ring = h_buf + 2 * 3 * HIDN;   // [64][512]
  float* rnn_ring = ctx_ring + 64 * HIDN;   // [64][512]
  float* m_ring  = rnn_ring + 64 * HIDN;    // [4][64]
  float* S_ring  = m_ring + 256;            // [4][64]
  float* P_ring  = S_ring + 256;            // [4][512][64] (transposed: d-major)
  float* z_ring  = P_ring + 4 * HIDN * 64;  // [4][64]

  __shared__ float xe[EE];
  __shared__ float xc[HIDN];
  __shared__ float hp[3][HIDN];
  __shared__ float gates[48];
  __shared__ float csto[12];
  __shared__ float ro[HIDN];
  __shared__ float ered[32];
  __shared__ float wexp[32];
  __shared__ float rs[4];

  if (tid < 12) csto[tid] = 0.f;

  for (int s = 0; s < NSTAGES; ++s) {
    // ---------- stage inputs: h(prev) for all 3 layers, layer-0 input ----------
    const float* hb = h_buf + (s & 1) * 1536;
    for (int i = tid; i < 1536; i += NTHR) (&hp[0][0])[i] = aload(hb + i);

    const int pa = s;  // layer-0 position
    if (pa < NPOS) {
      const int b0 = pa & 31, t0 = pa >> 5;
      const int g0 = gt[b0 * LL + t0];
      if (t0 == 0) {
        if (tid < EE) xe[tid] = (tid == g0) ? 1.f : 0.f;     // one-hot seed
        for (int i = tid; i < HIDN; i += NTHR)
          xc[i] = ctx_t[(size_t)b0 * TT * HIDN + i];          // context[b,0,:]
      } else {
        if (tid < EE) xe[tid] = emb[g0 * EE + tid];           // teacher forcing
        const float* cr = ctx_ring + ((pa - 32) & 63) * HIDN;
        for (int i = tid; i < HIDN; i += NTHR) xc[i] = aload(cr + i);
      }
    }
    __syncthreads();

    // ---------- LSTM: 48 gate-row dot products (12 per wave) ----------
#pragma unroll
    for (int jj = 0; jj < 12; ++jj) {
      const int r = wv + 4 * jj;             // task id 0..47
      const int l = r >> 4, g = (r >> 2) & 3, q = r & 3;
      const int pl = s - l;
      if (pl >= 0 && pl < NPOS) {
        const int R = (g << 9) + (bid << 2) + q;   // gate row in [0,2048)
        float acc = 0.f;
        if (l == 0) {
          const float* wi = wi0 + (size_t)R * 576;
          acc += wi[lane] * xe[lane];
#pragma unroll
          for (int k = 0; k < 8; ++k) acc += wi[64 + 64 * k + lane] * xc[64 * k + lane];
          const float* wh = wh0 + (size_t)R * 512;
#pragma unroll
          for (int k = 0; k < 8; ++k) acc += wh[64 * k + lane] * hp[0][64 * k + lane];
        } else {
          const float* wi = (l == 1 ? wi1 : wi2) + (size_t)R * 512;
          const float* xin = hp[l - 1];
#pragma unroll
          for (int k = 0; k < 8; ++k) acc += wi[64 * k + lane] * xin[64 * k + lane];
          const float* wh = (l == 1 ? wh1 : wh2) + (size_t)R * 512;
          const float* hh = hp[l];
#pragma unroll
          for (int k = 0; k < 8; ++k) acc += wh[64 * k + lane] * hh[64 * k + lane];
        }
        acc = wsum(acc);
        if (lane == 0) {
          const float* bi = l == 0 ? bi0 : (l == 1 ? bi1 : bi2);
          const float* bh = l == 0 ? bh0 : (l == 1 ? bh1 : bh2);
          gates[r] = acc + bi[R] + bh[R];
        }
      }
    }
    __syncthreads();

    // ---------- pointwise cell update (this block's 12 units) ----------
    if (tid < 12) {
      const int l = tid >> 2, q = tid & 3;
      const int pl = s - l;
      if (pl >= 0 && pl < NPOS) {
        const float gi = gates[(l << 4) + q];
        const float gf = gates[(l << 4) + 4 + q];
        const float gg = gates[(l << 4) + 8 + q];
        const float go = gates[(l << 4) + 12 + q];
        const float cn = sigm(gf) * csto[tid] + sigm(gi) * tanhf(gg);
        const float hn = sigm(go) * tanhf(cn);
        csto[tid] = cn;
        const int u = (bid << 2) + q;
        astore(h_buf + ((s + 1) & 1) * 1536 + (l << 9) + u, hn);
        if (l == 2) astore(rnn_ring + (pl & 63) * HIDN + u, hn);
      }
    }

    // ---------- attention phase 1 (blocks 0..63): energies + local softmax partials ----------
    const int p1 = s - 3;
    if (bid < 64 && p1 >= 0 && p1 < NPOS) {
      const int b1 = p1 & 31;
      const float* rr = rnn_ring + (p1 & 63) * HIDN;
      for (int i = tid; i < HIDN; i += NTHR) ro[i] = aload(rr + i);
      __syncthreads();
#pragma unroll
      for (int jj = 0; jj < 8; ++jj) {
        const int j = (wv << 3) + jj;
        const float* crow = ctx_t + ((size_t)b1 * TT + (bid << 5) + j) * HIDN;
        float a = 0.f;
#pragma unroll
        for (int k = 0; k < 8; ++k) a += crow[64 * k + lane] * ro[64 * k + lane];
        a = wsum(a);
        if (lane == 0) ered[j] = a;
      }
      __syncthreads();
      if (wv == 0) {
        const float e = (lane < 32) ? ered[lane] : -1e30f;
        const float m = wmax(e);
        const float w = (lane < 32) ? expf(e - m) : 0.f;
        const float Sv = wsum(w);
        if (lane < 32) wexp[lane] = w;
        if (lane == 0) {
          astore(m_ring + (p1 & 3) * 64 + bid, m);
          astore(S_ring + (p1 & 3) * 64 + bid, Sv);
        }
      }
      __syncthreads();
      float a0 = 0.f, a1 = 0.f;
      const size_t cbase = ((size_t)b1 * TT + (bid << 5)) * HIDN;
      for (int j = 0; j < 32; ++j) {
        const float w = wexp[j];
        const float* crow = ctx_t + cbase + (size_t)j * HIDN;
        a0 += w * crow[tid];
        a1 += w * crow[tid + 256];
      }
      float* Pb = P_ring + (p1 & 3) * (HIDN * 64);
      astore(Pb + tid * 64 + bid, a0);
      astore(Pb + (tid + 256) * 64 + bid, a1);
    }

    // ---------- attention phase 2 (all blocks, 4 dims each): combine partials ----------
    const int p2 = s - 4;
    if (p2 >= 0 && p2 < NPOS && wv == 0) {
      const int slot = p2 & 3;
      const float mi = aload(m_ring + slot * 64 + lane);
      const float Si = aload(S_ring + slot * 64 + lane);
      const float M = wmax(mi);
      const float esc = expf(mi - M);
      const float Z = wsum(Si * esc);
      const float* Pb = P_ring + slot * (HIDN * 64);
      float* cr = ctx_ring + (p2 & 63) * HIDN;
#pragma unroll
      for (int dd = 0; dd < 4; ++dd) {
        const int d = (bid << 2) + dd;
        const float sv = wsum(aload(Pb + d * 64 + lane) * esc);
        if (lane == 0) astore(cr + d, sv / Z);
      }
    }

    // ---------- projection phase 1 (blocks 64..127): z[v] = w_out[v] . feat ----------
    const int p3 = s - 5;
    if (bid >= 64 && bid < 128 && p3 >= 0 && p3 < NPOS) {
      const int v = bid - 64;
      const int slot = p3 & 63;
      const float* wr = w_out + v * 1024;
      float a = 0.f;
#pragma unroll
      for (int k = 0; k < 4; ++k) {
        const int c = tid + (k << 8);
        const float f = (c < 512) ? aload(rnn_ring + slot * HIDN + c)
                                  : aload(ctx_ring + slot * HIDN + (c - 512));
        a += wr[c] * f;
      }
      a = wsum(a);
      if (lane == 0) rs[wv] = a;
      __syncthreads();
      if (tid == 0)
        astore(z_ring + (p3 & 3) * 64 + v, rs[0] + rs[1] + rs[2] + rs[3] + b_out[v]);
    }

    // ---------- projection phase 2 (block 5): log_softmax + write output ----------
    const int p4 = s - 6;
    if (bid == 5 && p4 >= 0 && p4 < NPOS && wv == 0) {
      const int b4 = p4 & 31, t4 = p4 >> 5;
      const float z = aload(z_ring + (p4 & 3) * 64 + lane);
      const float M = wmax(z);
      const float ls = M + logf(wsum(expf(z - M)));
      out[((size_t)b4 * 99 + t4) * 64 + lane] = z - ls;
    }

    // ---------- grid barrier (monotonic count + generation flag) ----------
    __syncthreads();
    if (tid == 0) {
      const int tgt = s + 1;
      const int old = __hip_atomic_fetch_add(cnt, 1, __ATOMIC_ACQ_REL, __HIP_MEMORY_SCOPE_AGENT);
      if (old == tgt * NBLK - 1) {
        __hip_atomic_store(gen, tgt, __ATOMIC_RELEASE, __HIP_MEMORY_SCOPE_AGENT);
      } else {
        while (__hip_atomic_load(gen, __ATOMIC_ACQUIRE, __HIP_MEMORY_SCOPE_AGENT) < tgt)
          __builtin_amdgcn_s_sleep(1);
      }
    }
    __syncthreads();
  }
}

extern "C" void kernel_launch(void* const* d_in, const int* in_sizes, int n_in,
                              void* d_out, int out_size, void* d_ws, size_t ws_size,
                              hipStream_t stream) {
  (void)in_sizes; (void)n_in; (void)out_size; (void)ws_size;
  const float* ctx_t = (const float*)d_in[0];
  const int*   gt    = (const int*)d_in[1];
  const float* emb   = (const float*)d_in[3];
  const float* w_out = (const float*)d_in[4];
  const float* b_out = (const float*)d_in[5];
  const float* wi0 = (const float*)d_in[6];
  const float* wh0 = (const float*)d_in[7];
  const float* bi0 = (const float*)d_in[8];
  const float* bh0 = (const float*)d_in[9];
  const float* wi1 = (const float*)d_in[10];
  const float* wh1 = (const float*)d_in[11];
  const float* bi1 = (const float*)d_in[12];
  const float* bh1 = (const float*)d_in[13];
  const float* wi2 = (const float*)d_in[14];
  const float* wh2 = (const float*)d_in[15];
  const float* bi2 = (const float*)d_in[16];
  const float* bh2 = (const float*)d_in[17];
  float* out = (float*)d_out;
  float* ws  = (float*)d_ws;

  hipLaunchKernelGGL(speller_init, dim3(13), dim3(256), 0, stream, ws);

  void* args[] = {&ctx_t, &gt, &emb, &w_out, &b_out,
                  &wi0, &wh0, &bi0, &bh0,
                  &wi1, &wh1, &bi1, &bh1,
                  &wi2, &wh2, &bi2, &bh2,
                  &out, &ws};
  hipLaunchCooperativeKernel((void*)speller_main, dim3(NBLK), dim3(NTHR), args, 0, stream);
}

// Round 4
// 53498.975 us; speedup vs baseline: 2.5491x; 2.5491x over previous
//
#include <hip/hip_runtime.h>
#include <math.h>

#define NBLK 128
#define NTHR 512
#define NPOS 3168     // 99 steps * 32 batch
#define NSTAGES 3177  // last proj-phase2 at s = 3167 + 9
#define HIDN 512
#define TT 2048
#define LL 100

__device__ __forceinline__ float aload(const float* p) {
  return __hip_atomic_load((float*)p, __ATOMIC_RELAXED, __HIP_MEMORY_SCOPE_AGENT);
}
__device__ __forceinline__ void astore(float* p, float v) {
  __hip_atomic_store(p, v, __ATOMIC_RELAXED, __HIP_MEMORY_SCOPE_AGENT);
}
__device__ __forceinline__ float wsum(float v) {
#pragma unroll
  for (int o = 32; o; o >>= 1) v += __shfl_xor(v, o);
  return v;
}
__device__ __forceinline__ float wmax(float v) {
#pragma unroll
  for (int o = 32; o; o >>= 1) v = fmaxf(v, __shfl_xor(v, o));
  return v;
}
__device__ __forceinline__ float sigm(float x) { return 1.f / (1.f + expf(-x)); }

extern "C" __global__ void speller_init(float* ws) {
  const int i = blockIdx.x * blockDim.x + threadIdx.x;
  if (i < 3328) ws[i] = 0.f;  // arrive flags (256 ints) + h double buffers (3072 floats)
}

extern "C" __global__ __launch_bounds__(NTHR, 2)
void speller_main(const float* __restrict__ ctx_t, const int* __restrict__ gt,
                  const float* __restrict__ emb, const float* __restrict__ w_out,
                  const float* __restrict__ b_out,
                  const float* __restrict__ wi0, const float* __restrict__ wh0,
                  const float* __restrict__ bi0, const float* __restrict__ bh0,
                  const float* __restrict__ wi1, const float* __restrict__ wh1,
                  const float* __restrict__ bi1, const float* __restrict__ bh1,
                  const float* __restrict__ wi2, const float* __restrict__ wh2,
                  const float* __restrict__ bi2, const float* __restrict__ bh2,
                  float* __restrict__ out, float* __restrict__ ws)
{
  const int bid = blockIdx.x, tid = threadIdx.x;
  const int lane = tid & 63, wv = tid >> 6;
  const int ub = bid * 4;  // this block's 4 hidden units (per layer)

  // ---------------- workspace layout (195,968 floats = 783.9 KB) ----------------
  int*   arrive   = (int*)ws;               // [256] (128 used)
  float* h_buf    = ws + 256;               // [2][3][512]
  float* rnn_ring = ws + 3328;              // [8][512]
  float* ctx_ring = ws + 7424;              // [64][512]
  float* e_ring   = ws + 40192;             // [2][2048]
  float* w_ring   = ws + 44288;             // [2][2048]
  float* P_ring   = ws + 48384;             // [2][128][512]
  float* Q_ring   = ws + 179456;            // [2][16][512]
  float* z_ring   = ws + 195840;            // [2][64]

  __shared__ float sro[HIDN];   // rnn_out for attention energies
  __shared__ float swex[16];    // this block's 16 attention weights (phase C)
  __shared__ float gates[48];   // l*16 + g*4 + q
  __shared__ float csto[12];    // cell state, 4 units x 3 layers

  if (tid < 12) csto[tid] = 0.f;

  // ---------------- weight preload into VGPRs ----------------
  // waves 0,1: layer 0 (gates {0,1}/{2,3} x 4 units, 17 chunks incl. emb)
  // waves 2,3: layer 1 ; waves 4,5: layer 2 (16 chunks)
  const int lyr = wv >> 1;  // 0..2 for wv 0..5
  float wreg[8][17];
  float bsum[8];
  if (wv < 6) {
    if (lyr == 0) {
#pragma unroll
      for (int r = 0; r < 8; ++r) {
        const int R = (wv * 2 + (r >> 2)) * 512 + ub + (r & 3);
#pragma unroll
        for (int k = 0; k < 9; ++k) wreg[r][k] = wi0[(size_t)R * 576 + k * 64 + lane];
#pragma unroll
        for (int k = 0; k < 8; ++k) wreg[r][9 + k] = wh0[(size_t)R * 512 + k * 64 + lane];
        bsum[r] = bi0[R] + bh0[R];
      }
    } else {
      const float* wiL = (lyr == 1) ? wi1 : wi2;
      const float* whL = (lyr == 1) ? wh1 : wh2;
      const float* biL = (lyr == 1) ? bi1 : bi2;
      const float* bhL = (lyr == 1) ? bh1 : bh2;
#pragma unroll
      for (int r = 0; r < 8; ++r) {
        const int R = ((wv & 1) * 2 + (r >> 2)) * 512 + ub + (r & 3);
#pragma unroll
        for (int k = 0; k < 8; ++k) wreg[r][k] = wiL[(size_t)R * 512 + k * 64 + lane];
#pragma unroll
        for (int k = 0; k < 8; ++k) wreg[r][8 + k] = whL[(size_t)R * 512 + k * 64 + lane];
        bsum[r] = biL[R] + bhL[R];
      }
    }
  }
  // projection weights: wave 6 of blocks 0..63 holds w_out row `bid`
  float wp[16];
  float bz = 0.f;
  if (bid < 64 && wv == 6) {
#pragma unroll
    for (int k = 0; k < 16; ++k) wp[k] = w_out[(size_t)bid * 1024 + k * 64 + lane];
    bz = b_out[bid];
  }

  for (int s = 0; s < NSTAGES; ++s) {
    const float* hb = h_buf + (s & 1) * 1536;
    const int p1 = s - 3, p2 = s - 4, p3 = s - 5, p4 = s - 6,
              p5 = s - 7, p6 = s - 8, p7 = s - 9;

    // ---- pre-barrier LDS staging ----
    if (p1 >= 0 && p1 < NPOS) sro[tid] = aload(rnn_ring + (p1 & 7) * 512 + tid);
    if (p3 >= 0 && p3 < NPOS && tid < 16)
      swex[tid] = aload(w_ring + (p3 & 1) * 2048 + bid * 16 + tid);

    // ---- LSTM gather + register dot products ----
    if (wv < 6) {
      const int pL = s - lyr;
      if (pL >= 0 && pL < NPOS) {
        float x[17];
        if (lyr == 0) {
          const int b0 = s & 31, t0 = s >> 5;
          const int g0 = gt[b0 * LL + t0];
          if (t0 == 0) {
            x[0] = (lane == g0) ? 1.f : 0.f;
            const float* cb = ctx_t + (size_t)b0 * TT * HIDN;
#pragma unroll
            for (int k = 0; k < 8; ++k) x[1 + k] = cb[k * 64 + lane];
          } else {
            x[0] = emb[g0 * 64 + lane];
            const float* cr = ctx_ring + ((s - 32) & 63) * 512;
#pragma unroll
            for (int k = 0; k < 8; ++k) x[1 + k] = aload(cr + k * 64 + lane);
          }
#pragma unroll
          for (int k = 0; k < 8; ++k) x[9 + k] = aload(hb + k * 64 + lane);
#pragma unroll
          for (int r = 0; r < 8; ++r) {
            float a = 0.f;
#pragma unroll
            for (int k = 0; k < 17; ++k) a += wreg[r][k] * x[k];
            a = wsum(a) + bsum[r];
            if (lane == 0) gates[(wv * 2 + (r >> 2)) * 4 + (r & 3)] = a;
          }
        } else {
          const int base = (lyr - 1) * 512;  // input = h_{lyr-1}, recur = h_{lyr}
#pragma unroll
          for (int k = 0; k < 8; ++k) x[k]     = aload(hb + base + k * 64 + lane);
#pragma unroll
          for (int k = 0; k < 8; ++k) x[8 + k] = aload(hb + base + 512 + k * 64 + lane);
#pragma unroll
          for (int r = 0; r < 8; ++r) {
            float a = 0.f;
#pragma unroll
            for (int k = 0; k < 16; ++k) a += wreg[r][k] * x[k];
            a = wsum(a) + bsum[r];
            if (lane == 0) gates[lyr * 16 + ((wv & 1) * 2 + (r >> 2)) * 4 + (r & 3)] = a;
          }
        }
      }
    }
    __syncthreads();  // gates, sro, swex visible block-wide

    // ---- pointwise cell update (4 units x 3 layers) ----
    if (tid < 12) {
      const int l = tid >> 2, q = tid & 3;
      const int pl = s - l;
      if (pl >= 0 && pl < NPOS) {
        const float gi = gates[l * 16 + q];
        const float gf = gates[l * 16 + 4 + q];
        const float gg = gates[l * 16 + 8 + q];
        const float go = gates[l * 16 + 12 + q];
        const float cn = sigm(gf) * csto[tid] + sigm(gi) * tanhf(gg);
        const float hn = sigm(go) * tanhf(cn);
        csto[tid] = cn;
        const int u = ub + q;
        astore(h_buf + ((s + 1) & 1) * 1536 + l * 512 + u, hn);
        if (l == 2) astore(rnn_ring + (pl & 7) * 512 + u, hn);
      }
    }

    // ---- attn A: energies, 16 T-rows per block (2 per wave) ----
    if (p1 >= 0 && p1 < NPOS) {
      const int b1 = p1 & 31;
#pragma unroll
      for (int jj = 0; jj < 2; ++jj) {
        const int j = bid * 16 + wv * 2 + jj;
        const float* crow = ctx_t + ((size_t)b1 * TT + j) * HIDN;
        float a = 0.f;
#pragma unroll
        for (int k = 0; k < 8; ++k) a += crow[k * 64 + lane] * sro[k * 64 + lane];
        a = wsum(a);
        if (lane == 0) astore(e_ring + (p1 & 1) * 2048 + j, a);
      }
    }

    // ---- attn B: global softmax over 2048 energies (block 17, wave 7) ----
    if (bid == 17 && wv == 7 && p2 >= 0 && p2 < NPOS) {
      const float* eb = e_ring + (p2 & 1) * 2048;
      float e[32];
#pragma unroll
      for (int k = 0; k < 32; ++k) e[k] = aload(eb + k * 64 + lane);
      float m = e[0];
#pragma unroll
      for (int k = 1; k < 32; ++k) m = fmaxf(m, e[k]);
      m = wmax(m);
      float ssum = 0.f;
#pragma unroll
      for (int k = 0; k < 32; ++k) { e[k] = expf(e[k] - m); ssum += e[k]; }
      ssum = wsum(ssum);
      const float inv = 1.f / ssum;
      float* wb = w_ring + (p2 & 1) * 2048;
#pragma unroll
      for (int k = 0; k < 32; ++k) astore(wb + k * 64 + lane, e[k] * inv);
    }

    // ---- attn C: weighted partial sum, 16 rows per block (all 128 blocks) ----
    if (p3 >= 0 && p3 < NPOS) {
      const int b3 = p3 & 31;
      const float* cb3 = ctx_t + ((size_t)b3 * TT + bid * 16) * HIDN;
      float a0 = 0.f;
#pragma unroll
      for (int j = 0; j < 16; ++j) a0 += swex[j] * cb3[j * HIDN + tid];
      astore(P_ring + (p3 & 1) * (128 * 512) + bid * 512 + tid, a0);
    }

    // ---- attn D1: 128 -> 16 partial combine (blocks 0..15) ----
    if (bid < 16 && p4 >= 0 && p4 < NPOS) {
      const float* Pb = P_ring + (p4 & 1) * (128 * 512) + (bid * 8) * 512;
      float q0 = 0.f;
#pragma unroll
      for (int k = 0; k < 8; ++k) q0 += aload(Pb + k * 512 + tid);
      astore(Q_ring + (p4 & 1) * 8192 + bid * 512 + tid, q0);
    }

    // ---- attn D2: 16 -> 1 combine (block 16) ----
    if (bid == 16 && p5 >= 0 && p5 < NPOS) {
      const float* Qb = Q_ring + (p5 & 1) * 8192;
      float c0 = 0.f;
#pragma unroll
      for (int k = 0; k < 16; ++k) c0 += aload(Qb + k * 512 + tid);
      astore(ctx_ring + (p5 & 63) * 512 + tid, c0);
    }

    // ---- proj1: z[v] = w_out[v] . [rnn|ctx] (wave 6 of blocks 0..63) ----
    if (bid < 64 && wv == 6 && p6 >= 0 && p6 < NPOS) {
      const float* rr6 = rnn_ring + (p6 & 7) * 512;
      const float* cr6 = ctx_ring + (p6 & 63) * 512;
      float a = 0.f;
#pragma unroll
      for (int k = 0; k < 8; ++k) a += wp[k] * aload(rr6 + k * 64 + lane);
#pragma unroll
      for (int k = 0; k < 8; ++k) a += wp[8 + k] * aload(cr6 + k * 64 + lane);
      a = wsum(a);
      if (lane == 0) astore(z_ring + (p6 & 1) * 64 + bid, a + bz);
    }

    // ---- proj2: log_softmax + output write (block 18, wave 7) ----
    if (bid == 18 && wv == 7 && p7 >= 0 && p7 < NPOS) {
      const float z = aload(z_ring + (p7 & 1) * 64 + lane);
      const float M = wmax(z);
      const float ls = M + logf(wsum(expf(z - M)));
      out[((size_t)(p7 & 31) * 99 + (p7 >> 5)) * 64 + lane] = z - ls;
    }

    // ---- grid barrier ----
    // Drain each wave's own outstanding global stores before arrival:
    // s_barrier does not wait other waves' vmem; vmcnt is per-wave.
    asm volatile("s_waitcnt vmcnt(0)" ::: "memory");
    __syncthreads();
    if (tid == 0)
      __hip_atomic_store(arrive + bid, s + 1, __ATOMIC_RELEASE, __HIP_MEMORY_SCOPE_AGENT);
    if (tid < NBLK)
      while (__hip_atomic_load(arrive + tid, __ATOMIC_ACQUIRE, __HIP_MEMORY_SCOPE_AGENT) < s + 1)
        __builtin_amdgcn_s_sleep(2);
    __syncthreads();
  }
}

extern "C" void kernel_launch(void* const* d_in, const int* in_sizes, int n_in,
                              void* d_out, int out_size, void* d_ws, size_t ws_size,
                              hipStream_t stream) {
  (void)in_sizes; (void)n_in; (void)out_size; (void)ws_size;
  const float* ctx_t = (const float*)d_in[0];
  const int*   gt    = (const int*)d_in[1];
  const float* emb   = (const float*)d_in[3];
  const float* w_out = (const float*)d_in[4];
  const float* b_out = (const float*)d_in[5];
  const float* wi0 = (const float*)d_in[6];
  const float* wh0 = (const float*)d_in[7];
  const float* bi0 = (const float*)d_in[8];
  const float* bh0 = (const float*)d_in[9];
  const float* wi1 = (const float*)d_in[10];
  const float* wh1 = (const float*)d_in[11];
  const float* bi1 = (const float*)d_in[12];
  const float* bh1 = (const float*)d_in[13];
  const float* wi2 = (const float*)d_in[14];
  const float* wh2 = (const float*)d_in[15];
  const float* bi2 = (const float*)d_in[16];
  const float* bh2 = (const float*)d_in[17];
  float* out = (float*)d_out;
  float* ws  = (float*)d_ws;

  hipLaunchKernelGGL(speller_init, dim3(13), dim3(256), 0, stream, ws);

  void* args[] = {&ctx_t, &gt, &emb, &w_out, &b_out,
                  &wi0, &wh0, &bi0, &bh0,
                  &wi1, &wh1, &bi1, &bh1,
                  &wi2, &wh2, &bi2, &bh2,
                  &out, &ws};
  hipLaunchCooperativeKernel((void*)speller_main, dim3(NBLK), dim3(NTHR), args, 0, stream);
}